// Round 1
// baseline (255.324 us; speedup 1.0000x reference)
//
#include <hip/hip_runtime.h>
#include <hip/hip_bf16.h>
#include <stdint.h>

// ---------- helpers ----------
typedef __attribute__((ext_vector_type(8))) short s16x8;
typedef __attribute__((ext_vector_type(4))) float f32x4;

__device__ __forceinline__ unsigned short f2bf(float f) {
  union { float f; unsigned int u; } v; v.f = f;
  unsigned int r = (v.u + 0x7fffu + ((v.u >> 16) & 1u)) >> 16;
  return (unsigned short)r;
}
__device__ __forceinline__ float bf2f(unsigned short h) {
  union { float f; unsigned int u; } v; v.u = ((unsigned int)h) << 16; return v.f;
}

// async global->LDS, 16B per lane; lds base must be wave-uniform, dest = base + lane*16
__device__ __forceinline__ void async_copy16(const unsigned short* g, unsigned short* lds_base) {
  __builtin_amdgcn_global_load_lds(
      (const __attribute__((address_space(1))) unsigned int*)g,
      (__attribute__((address_space(3))) unsigned int*)lds_base,
      16, 0, 0);
}

// ---------- fp32 -> bf16 convert ----------
__global__ __launch_bounds__(256) void cvt_kernel(const float* __restrict__ src,
                                                  unsigned short* __restrict__ dst, int n4) {
  int i = blockIdx.x * 256 + threadIdx.x;
  if (i < n4) {
    float4 v = ((const float4*)src)[i];
    ushort4 o;
    o.x = f2bf(v.x); o.y = f2bf(v.y); o.z = f2bf(v.z); o.w = f2bf(v.w);
    ((ushort4*)dst)[i] = o;
  }
}

// ---------- LayerNorm: one block per row of 1024 ----------
__global__ __launch_bounds__(256) void ln_kernel(const float* __restrict__ x,
                                                 const float* __restrict__ gamma,
                                                 const float* __restrict__ beta,
                                                 unsigned short* __restrict__ h) {
  const int row = blockIdx.x;
  const int t = threadIdx.x;
  const float4 v = ((const float4*)(x + (size_t)row * 1024))[t];
  float s  = v.x + v.y + v.z + v.w;
  float s2 = v.x*v.x + v.y*v.y + v.z*v.z + v.w*v.w;
#pragma unroll
  for (int o = 32; o > 0; o >>= 1) {
    s  += __shfl_down(s,  o, 64);
    s2 += __shfl_down(s2, o, 64);
  }
  __shared__ float rs[4], rs2[4];
  const int wid = t >> 6;
  if ((t & 63) == 0) { rs[wid] = s; rs2[wid] = s2; }
  __syncthreads();
  const float S  = rs[0] + rs[1] + rs[2] + rs[3];
  const float S2 = rs2[0] + rs2[1] + rs2[2] + rs2[3];
  const float mu  = S * (1.f / 1024.f);
  const float inv = rsqrtf(S2 * (1.f / 1024.f) - mu * mu + 1e-5f);
  const float4 g = ((const float4*)gamma)[t];
  const float4 b = ((const float4*)beta)[t];
  ushort4 o;
  o.x = f2bf((v.x - mu) * inv * g.x + b.x);
  o.y = f2bf((v.y - mu) * inv * g.y + b.y);
  o.z = f2bf((v.z - mu) * inv * g.z + b.z);
  o.w = f2bf((v.w - mu) * inv * g.w + b.w);
  ((ushort4*)(h + (size_t)row * 1024))[t] = o;
}

// ---------- q/k projection from base = uv[:, 2E : 2E+S] ----------
__global__ __launch_bounds__(256) void qk_kernel(const unsigned short* __restrict__ uv,
                                                 const float* __restrict__ qkw,
                                                 const float* __restrict__ qkb,
                                                 unsigned short* __restrict__ q,
                                                 unsigned short* __restrict__ k,
                                                 int NU, int baseoff, int S, int total) {
  int i = blockIdx.x * 256 + threadIdx.x;
  if (i < total) {
    int n = i / S, s = i - n * S;
    float base = bf2f(uv[(size_t)n * NU + baseoff + s]);
    q[i] = f2bf(base * qkw[s]     + qkb[s]);
    k[i] = f2bf(base * qkw[S + s] + qkb[S + s]);
  }
}

// ---------- transpose v: vT[e][m] = uv[m][E + e] ----------
__global__ __launch_bounds__(256) void transpose_v(const unsigned short* __restrict__ uv,
                                                   unsigned short* __restrict__ vT,
                                                   int n, int NU, int E) {
  __shared__ unsigned short tile[64][68];
  const int tm = blockIdx.x * 64;   // m tile
  const int te = blockIdx.y * 64;   // e tile
  const int t = threadIdx.x;
  const int r  = t >> 4;            // 0..15
  const int c4 = (t & 15) * 4;      // 0..60
#pragma unroll
  for (int i = 0; i < 4; ++i) {
    int row = i * 16 + r;
    ushort4 v = *(const ushort4*)(uv + (size_t)(tm + row) * NU + E + te + c4);
    tile[row][c4 + 0] = v.x; tile[row][c4 + 1] = v.y;
    tile[row][c4 + 2] = v.z; tile[row][c4 + 3] = v.w;
  }
  __syncthreads();
#pragma unroll
  for (int i = 0; i < 4; ++i) {
    int erow = i * 16 + r;
    ushort4 o;
    o.x = tile[c4 + 0][erow]; o.y = tile[c4 + 1][erow];
    o.z = tile[c4 + 2][erow]; o.w = tile[c4 + 3][erow];
    *(ushort4*)(vT + (size_t)(te + erow) * n + tm + c4) = o;
  }
}

// ---------- bf16 MFMA GEMM, 128x128 tile, B^T layout (B stored [N][K]) ----------
// EPI 0: silu(acc + bias[col])          -> bf16 D
// EPI 1: (max(acc,0))^2 / 128           -> bf16 D
// EPI 2: acc * U[row][col]              -> bf16 D
// EPI 3: acc + bias[col] + X[row][col]  -> f32  D
template <int EPI>
__global__ __launch_bounds__(256) void gemm_bt(const unsigned short* __restrict__ A, int lda,
                                               const unsigned short* __restrict__ B, int ldb,
                                               void* __restrict__ D, int ldd, int K,
                                               const float* __restrict__ bias,
                                               const unsigned short* __restrict__ U, int ldu,
                                               const float* __restrict__ X, int ldx) {
  __shared__ unsigned short As[128 * 64];
  __shared__ unsigned short Bs[128 * 64];
  const int tid  = threadIdx.x;
  const int wid  = tid >> 6;
  const int lane = tid & 63;
  const int bm = blockIdx.x * 128;
  const int bn = blockIdx.y * 128;
  const int wm = (wid >> 1) * 64;
  const int wn = (wid & 1) * 64;

  f32x4 acc[4][4] = {};

  const int srow = lane >> 3;        // row within 8-row chunk
  const int scol = (lane & 7) * 8;   // element col within 64
  const int lrow = lane & 15;
  const int kgrp = (lane >> 4) * 8;

  for (int k0 = 0; k0 < K; k0 += 64) {
#pragma unroll
    for (int i = 0; i < 4; ++i) {
      const int chunk = wid * 4 + i;          // 0..15, wave-uniform
      const int row = chunk * 8 + srow;       // 0..127
      async_copy16(A + (size_t)(bm + row) * lda + k0 + scol, &As[chunk * 512]);
      async_copy16(B + (size_t)(bn + row) * ldb + k0 + scol, &Bs[chunk * 512]);
    }
    __syncthreads();   // drains vmcnt before barrier (compiler-inserted)
#pragma unroll
    for (int ks = 0; ks < 2; ++ks) {
      s16x8 a[4], b[4];
#pragma unroll
      for (int i = 0; i < 4; ++i)
        a[i] = *(const s16x8*)&As[(wm + i * 16 + lrow) * 64 + ks * 32 + kgrp];
#pragma unroll
      for (int j = 0; j < 4; ++j)
        b[j] = *(const s16x8*)&Bs[(wn + j * 16 + lrow) * 64 + ks * 32 + kgrp];
#pragma unroll
      for (int i = 0; i < 4; ++i)
#pragma unroll
        for (int j = 0; j < 4; ++j)
          acc[i][j] = __builtin_amdgcn_mfma_f32_16x16x32_bf16(a[i], b[j], acc[i][j], 0, 0, 0);
    }
    __syncthreads();
  }

  const int rbase = (lane >> 4) * 4;
  const int cloc  = lane & 15;
#pragma unroll
  for (int i = 0; i < 4; ++i) {
#pragma unroll
    for (int j = 0; j < 4; ++j) {
      const int col = bn + wn + j * 16 + cloc;
#pragma unroll
      for (int r = 0; r < 4; ++r) {
        const int row = bm + wm + i * 16 + rbase + r;
        float v = acc[i][j][r];
        if constexpr (EPI == 0) {
          v += bias[col];
          float sv = v / (1.f + __expf(-v));
          ((unsigned short*)D)[(size_t)row * ldd + col] = f2bf(sv);
        } else if constexpr (EPI == 1) {
          float z = fmaxf(v, 0.f);
          ((unsigned short*)D)[(size_t)row * ldd + col] = f2bf(z * z * (1.f / 128.f));
        } else if constexpr (EPI == 2) {
          float u = bf2f(U[(size_t)row * ldu + col]);
          ((unsigned short*)D)[(size_t)row * ldd + col] = f2bf(v * u);
        } else {
          ((float*)D)[(size_t)row * ldd + col] = v + bias[col] + X[(size_t)row * ldx + col];
        }
      }
    }
  }
}

// ---------- launch ----------
extern "C" void kernel_launch(void* const* d_in, const int* in_sizes, int n_in,
                              void* d_out, int out_size, void* d_ws, size_t ws_size,
                              hipStream_t stream) {
  const float* x    = (const float*)d_in[0];
  const float* ln_g = (const float*)d_in[1];
  const float* ln_b = (const float*)d_in[2];
  const float* uv_w = (const float*)d_in[3];
  const float* uv_b = (const float*)d_in[4];
  const float* qk_w = (const float*)d_in[5];
  const float* qk_b = (const float*)d_in[6];
  const float* o_w  = (const float*)d_in[7];
  const float* o_b  = (const float*)d_in[8];
  float* out = (float*)d_out;

  const int H = 1024, E = 2048, S = 128;
  const int NU = 2 * E + S;          // 4224
  const int n = in_sizes[0] / H;     // 4096

  char* p = (char*)d_ws;
  unsigned short* h_bf   = (unsigned short*)p; p += (size_t)n * H * 2;
  unsigned short* uvw_bf = (unsigned short*)p; p += (size_t)NU * H * 2;
  unsigned short* ow_bf  = (unsigned short*)p; p += (size_t)H * E * 2;
  unsigned short* uv_bf  = (unsigned short*)p; p += (size_t)n * NU * 2;
  unsigned short* q_bf   = (unsigned short*)p; p += (size_t)n * S * 2;
  unsigned short* k_bf   = (unsigned short*)p; p += (size_t)n * S * 2;
  unsigned short* vT_bf  = (unsigned short*)p; p += (size_t)E * n * 2;
  unsigned short* ker_bf = (unsigned short*)p; p += (size_t)n * n * 2;
  unsigned short* ug_bf  = (unsigned short*)p; p += (size_t)n * E * 2;

  int n4;
  n4 = NU * H / 4; cvt_kernel<<<(n4 + 255) / 256, 256, 0, stream>>>(uv_w, uvw_bf, n4);
  n4 = H * E / 4;  cvt_kernel<<<(n4 + 255) / 256, 256, 0, stream>>>(o_w, ow_bf, n4);

  ln_kernel<<<n, 256, 0, stream>>>(x, ln_g, ln_b, h_bf);

  // uv = silu(h @ uv_w^T + uv_b)
  gemm_bt<0><<<dim3(n / 128, NU / 128), 256, 0, stream>>>(
      h_bf, H, uvw_bf, H, uv_bf, NU, H, uv_b, nullptr, 0, nullptr, 0);

  int tq = n * S;
  qk_kernel<<<(tq + 255) / 256, 256, 0, stream>>>(uv_bf, qk_w, qk_b, q_bf, k_bf, NU, 2 * E, S, tq);

  transpose_v<<<dim3(n / 64, E / 64), 256, 0, stream>>>(uv_bf, vT_bf, n, NU, E);

  // kernel = relu(q @ k^T / sqrt(128))^2
  gemm_bt<1><<<dim3(n / 128, n / 128), 256, 0, stream>>>(
      q_bf, S, k_bf, S, ker_bf, n, S, nullptr, nullptr, 0, nullptr, 0);

  // ug = u * (kernel @ v)
  gemm_bt<2><<<dim3(n / 128, E / 128), 256, 0, stream>>>(
      ker_bf, n, vT_bf, n, ug_bf, E, n, nullptr, uv_bf, NU, nullptr, 0);

  // out = ug @ o_w^T + o_b + x
  gemm_bt<3><<<dim3(n / 128, H / 128), 256, 0, stream>>>(
      ug_bf, E, ow_bf, E, out, H, E, o_b, nullptr, 0, x, H);
}

// Round 2
// 216.002 us; speedup vs baseline: 1.1820x; 1.1820x over previous
//
#include <hip/hip_runtime.h>
#include <hip/hip_bf16.h>
#include <stdint.h>

// ---------- helpers ----------
typedef __attribute__((ext_vector_type(8))) short s16x8;
typedef __attribute__((ext_vector_type(4))) float f32x4;

__device__ __forceinline__ unsigned short f2bf(float f) {
  union { float f; unsigned int u; } v; v.f = f;
  unsigned int r = (v.u + 0x7fffu + ((v.u >> 16) & 1u)) >> 16;
  return (unsigned short)r;
}
__device__ __forceinline__ float bf2f(unsigned short h) {
  union { float f; unsigned int u; } v; v.u = ((unsigned int)h) << 16; return v.f;
}

// async global->LDS, 16B per lane; lds base must be wave-uniform, HW adds lane*16
__device__ __forceinline__ void async_copy16(const unsigned short* g, unsigned short* lds_base) {
  __builtin_amdgcn_global_load_lds(
      (const __attribute__((address_space(1))) unsigned int*)g,
      (__attribute__((address_space(3))) unsigned int*)lds_base,
      16, 0, 0);
}

// ---------- fp32 -> bf16 convert ----------
__global__ __launch_bounds__(256) void cvt_kernel(const float* __restrict__ src,
                                                  unsigned short* __restrict__ dst, int n4) {
  int i = blockIdx.x * 256 + threadIdx.x;
  if (i < n4) {
    float4 v = ((const float4*)src)[i];
    ushort4 o;
    o.x = f2bf(v.x); o.y = f2bf(v.y); o.z = f2bf(v.z); o.w = f2bf(v.w);
    ((ushort4*)dst)[i] = o;
  }
}

// ---------- LayerNorm: one block per row of 1024 ----------
__global__ __launch_bounds__(256) void ln_kernel(const float* __restrict__ x,
                                                 const float* __restrict__ gamma,
                                                 const float* __restrict__ beta,
                                                 unsigned short* __restrict__ h) {
  const int row = blockIdx.x;
  const int t = threadIdx.x;
  const float4 v = ((const float4*)(x + (size_t)row * 1024))[t];
  float s  = v.x + v.y + v.z + v.w;
  float s2 = v.x*v.x + v.y*v.y + v.z*v.z + v.w*v.w;
#pragma unroll
  for (int o = 32; o > 0; o >>= 1) {
    s  += __shfl_down(s,  o, 64);
    s2 += __shfl_down(s2, o, 64);
  }
  __shared__ float rs[4], rs2[4];
  const int wid = t >> 6;
  if ((t & 63) == 0) { rs[wid] = s; rs2[wid] = s2; }
  __syncthreads();
  const float S  = rs[0] + rs[1] + rs[2] + rs[3];
  const float S2 = rs2[0] + rs2[1] + rs2[2] + rs2[3];
  const float mu  = S * (1.f / 1024.f);
  const float inv = rsqrtf(S2 * (1.f / 1024.f) - mu * mu + 1e-5f);
  const float4 g = ((const float4*)gamma)[t];
  const float4 b = ((const float4*)beta)[t];
  ushort4 o;
  o.x = f2bf((v.x - mu) * inv * g.x + b.x);
  o.y = f2bf((v.y - mu) * inv * g.y + b.y);
  o.z = f2bf((v.z - mu) * inv * g.z + b.z);
  o.w = f2bf((v.w - mu) * inv * g.w + b.w);
  ((ushort4*)(h + (size_t)row * 1024))[t] = o;
}

// ---------- q/k projection from base = uv[:, 2E : 2E+S] ----------
__global__ __launch_bounds__(256) void qk_kernel(const unsigned short* __restrict__ uv,
                                                 const float* __restrict__ qkw,
                                                 const float* __restrict__ qkb,
                                                 unsigned short* __restrict__ q,
                                                 unsigned short* __restrict__ k,
                                                 int NU, int baseoff, int S, int total) {
  int i = blockIdx.x * 256 + threadIdx.x;
  if (i < total) {
    int n = i / S, s = i - n * S;
    float base = bf2f(uv[(size_t)n * NU + baseoff + s]);
    q[i] = f2bf(base * qkw[s]     + qkb[s]);
    k[i] = f2bf(base * qkw[S + s] + qkb[S + s]);
  }
}

// ---------- transpose v: vT[e][m] = uv[m][E + e] ----------
__global__ __launch_bounds__(256) void transpose_v(const unsigned short* __restrict__ uv,
                                                   unsigned short* __restrict__ vT,
                                                   int n, int NU, int E) {
  __shared__ unsigned short tile[64][68];
  const int tm = blockIdx.x * 64;
  const int te = blockIdx.y * 64;
  const int t = threadIdx.x;
  const int r  = t >> 4;
  const int c4 = (t & 15) * 4;
#pragma unroll
  for (int i = 0; i < 4; ++i) {
    int row = i * 16 + r;
    ushort4 v = *(const ushort4*)(uv + (size_t)(tm + row) * NU + E + te + c4);
    tile[row][c4 + 0] = v.x; tile[row][c4 + 1] = v.y;
    tile[row][c4 + 2] = v.z; tile[row][c4 + 3] = v.w;
  }
  __syncthreads();
#pragma unroll
  for (int i = 0; i < 4; ++i) {
    int erow = i * 16 + r;
    ushort4 o;
    o.x = tile[c4 + 0][erow]; o.y = tile[c4 + 1][erow];
    o.z = tile[c4 + 2][erow]; o.w = tile[c4 + 3][erow];
    *(ushort4*)(vT + (size_t)(te + erow) * n + tm + c4) = o;
  }
}

// ---------- OLD 128x128 2-phase GEMM (kept for GEMM2, K=128) ----------
// EPI 1: (max(acc,0))^2 / 128 -> bf16 D
template <int EPI>
__global__ __launch_bounds__(256) void gemm_bt(const unsigned short* __restrict__ A, int lda,
                                               const unsigned short* __restrict__ B, int ldb,
                                               void* __restrict__ D, int ldd, int K) {
  __shared__ unsigned short As[128 * 64];
  __shared__ unsigned short Bs[128 * 64];
  const int tid  = threadIdx.x;
  const int wid  = tid >> 6;
  const int lane = tid & 63;
  const int bm = blockIdx.x * 128;
  const int bn = blockIdx.y * 128;
  const int wm = (wid >> 1) * 64;
  const int wn = (wid & 1) * 64;

  f32x4 acc[4][4] = {};

  const int srow = lane >> 3;
  const int scol = (lane & 7) * 8;
  const int lrow = lane & 15;
  const int kgrp = (lane >> 4) * 8;

  for (int k0 = 0; k0 < K; k0 += 64) {
#pragma unroll
    for (int i = 0; i < 4; ++i) {
      const int chunk = wid * 4 + i;
      const int row = chunk * 8 + srow;
      async_copy16(A + (size_t)(bm + row) * lda + k0 + scol, &As[chunk * 512]);
      async_copy16(B + (size_t)(bn + row) * ldb + k0 + scol, &Bs[chunk * 512]);
    }
    __syncthreads();
#pragma unroll
    for (int ks = 0; ks < 2; ++ks) {
      s16x8 a[4], b[4];
#pragma unroll
      for (int i = 0; i < 4; ++i)
        a[i] = *(const s16x8*)&As[(wm + i * 16 + lrow) * 64 + ks * 32 + kgrp];
#pragma unroll
      for (int j = 0; j < 4; ++j)
        b[j] = *(const s16x8*)&Bs[(wn + j * 16 + lrow) * 64 + ks * 32 + kgrp];
#pragma unroll
      for (int i = 0; i < 4; ++i)
#pragma unroll
        for (int j = 0; j < 4; ++j)
          acc[i][j] = __builtin_amdgcn_mfma_f32_16x16x32_bf16(a[i], b[j], acc[i][j], 0, 0, 0);
    }
    __syncthreads();
  }

  const int rbase = (lane >> 4) * 4;
  const int cloc  = lane & 15;
#pragma unroll
  for (int i = 0; i < 4; ++i) {
#pragma unroll
    for (int j = 0; j < 4; ++j) {
      const int col = bn + wn + j * 16 + cloc;
#pragma unroll
      for (int r = 0; r < 4; ++r) {
        const int row = bm + wm + i * 16 + rbase + r;
        float v = acc[i][j][r];
        if constexpr (EPI == 1) {
          float z = fmaxf(v, 0.f);
          ((unsigned short*)D)[(size_t)row * ldd + col] = f2bf(z * z * (1.f / 128.f));
        }
      }
    }
  }
}

// ---------- NEW pipelined GEMM: BM=256 BN=128 BK=64, 3-buffer lookahead-2 ----------
// counted vmcnt(6) at tile boundary (never 0 in steady state), XOR-swizzled LDS,
// setprio around MFMA clusters. 512 threads = 8 waves (4M x 2N), per-wave 64x64.
// Race-freedom: tile t reads buf[t%3]; loads issued during tile t target
// buf[(t+2)%3], which tiles t and t+1 never touch; boundary vmcnt(6)+barrier
// retires tile t+1's 6 loads (issued during t-1) before tile t+1 is read.
// EPI 0: silu(acc + bias[col])          -> bf16 D
// EPI 2: acc * U[row][col]              -> bf16 D
// EPI 3: acc + bias[col] + X[row][col]  -> f32  D
template <int EPI>
__global__ __launch_bounds__(512, 2) void gemm_pipe(const unsigned short* __restrict__ A, int lda,
                                                    const unsigned short* __restrict__ B, int ldb,
                                                    void* __restrict__ D, int ldd, int K,
                                                    const float* __restrict__ bias,
                                                    const unsigned short* __restrict__ U, int ldu,
                                                    const float* __restrict__ X, int ldx) {
  __shared__ unsigned short As[3][256 * 64];   // 96 KB
  __shared__ unsigned short Bs[3][128 * 64];   // 48 KB
  const int tid  = threadIdx.x;
  const int wid  = tid >> 6;
  const int lane = tid & 63;
  const int bm = blockIdx.x * 256;
  const int bn = blockIdx.y * 128;
  const int wr = wid >> 1;        // 0..3 -> rows wr*64
  const int wc = wid & 1;         // 0..1 -> cols wc*64
  const int lrow = lane & 15;
  const int kgrp = (lane >> 4) * 8;
  const int swz  = (lrow & 7) * 8;   // read-side XOR swizzle (elements)

  // staging: per-issue 512 threads cover 64 rows x 64 cols; thread -> row tid>>3,
  // 16B slot (tid&7); source slot XOR'd so linear LDS + swizzled read match (rule #21)
  const int srow  = tid >> 3;                     // 0..63
  const int sslot = (tid & 7) ^ (srow & 7);
  const unsigned short* pA = A + (size_t)(bm + srow) * lda + sslot * 8;
  const unsigned short* pB = B + (size_t)(bn + srow) * ldb + sslot * 8;

#define STAGE3(bufidx, k0, i0, i1, jb)                                                   \
  async_copy16(pA + (size_t)((i0) * 64) * lda + (k0), &As[bufidx][((i0) * 64 + wid * 8) * 64]); \
  async_copy16(pA + (size_t)((i1) * 64) * lda + (k0), &As[bufidx][((i1) * 64 + wid * 8) * 64]); \
  async_copy16(pB + (size_t)((jb) * 64) * ldb + (k0), &Bs[bufidx][((jb) * 64 + wid * 8) * 64]);

  const int NT = K >> 6;   // K-tiles of 64 (requires NT >= 2)

  // prologue: stage tile0 -> buf0, tile1 -> buf1 (12 loads), wait for tile0 (keep 6 in flight)
  STAGE3(0, 0, 0, 1, 0);
  STAGE3(0, 0, 2, 3, 1);
  STAGE3(1, 64, 0, 1, 0);
  STAGE3(1, 64, 2, 3, 1);
  asm volatile("s_waitcnt vmcnt(6)" ::: "memory");
  __builtin_amdgcn_s_barrier();

  f32x4 acc[4][4] = {};
  int rb = 0, wb = 2;

  for (int t = 0; t < NT; ++t) {
    const bool pref = (t + 2) < NT;
    const int  k2   = (t + 2) << 6;
#pragma unroll
    for (int ks = 0; ks < 2; ++ks) {
      s16x8 a[4], b[4];
#pragma unroll
      for (int m = 0; m < 4; ++m) {
        const int row = wr * 64 + m * 16 + lrow;
        a[m] = *(const s16x8*)&As[rb][row * 64 + ((ks * 32 + kgrp) ^ swz)];
      }
#pragma unroll
      for (int n = 0; n < 4; ++n) {
        const int row = wc * 64 + n * 16 + lrow;
        b[n] = *(const s16x8*)&Bs[rb][row * 64 + ((ks * 32 + kgrp) ^ swz)];
      }
      if (pref) {
        if (ks == 0) { STAGE3(wb, k2, 0, 1, 0); }
        else         { STAGE3(wb, k2, 2, 3, 1); }
      }
      __builtin_amdgcn_s_barrier();
      asm volatile("s_waitcnt lgkmcnt(0)" ::: "memory");
      __builtin_amdgcn_sched_barrier(0);
      __builtin_amdgcn_s_setprio(1);
#pragma unroll
      for (int m = 0; m < 4; ++m)
#pragma unroll
        for (int n = 0; n < 4; ++n)
          acc[m][n] = __builtin_amdgcn_mfma_f32_16x16x32_bf16(a[m], b[n], acc[m][n], 0, 0, 0);
      __builtin_amdgcn_s_setprio(0);
      if (ks == 0) {
        __builtin_amdgcn_s_barrier();
      } else {
        // tile boundary: retire next tile's loads, keep the 6 just-issued in flight
        if (pref) { asm volatile("s_waitcnt vmcnt(6)" ::: "memory"); }
        else      { asm volatile("s_waitcnt vmcnt(0)" ::: "memory"); }
        __builtin_amdgcn_s_barrier();
      }
    }
    rb = (rb == 2) ? 0 : rb + 1;
    wb = (wb == 2) ? 0 : wb + 1;
  }
#undef STAGE3

  // epilogue
  const int rbase = (lane >> 4) * 4;
  const int cloc  = lane & 15;
#pragma unroll
  for (int m = 0; m < 4; ++m) {
#pragma unroll
    for (int n = 0; n < 4; ++n) {
      const int col = bn + wc * 64 + n * 16 + cloc;
#pragma unroll
      for (int r = 0; r < 4; ++r) {
        const int row = bm + wr * 64 + m * 16 + rbase + r;
        float v = acc[m][n][r];
        if constexpr (EPI == 0) {
          v += bias[col];
          float sv = v / (1.f + __expf(-v));
          ((unsigned short*)D)[(size_t)row * ldd + col] = f2bf(sv);
        } else if constexpr (EPI == 2) {
          float u = bf2f(U[(size_t)row * ldu + col]);
          ((unsigned short*)D)[(size_t)row * ldd + col] = f2bf(v * u);
        } else {
          ((float*)D)[(size_t)row * ldd + col] = v + bias[col] + X[(size_t)row * ldx + col];
        }
      }
    }
  }
}

// ---------- launch ----------
extern "C" void kernel_launch(void* const* d_in, const int* in_sizes, int n_in,
                              void* d_out, int out_size, void* d_ws, size_t ws_size,
                              hipStream_t stream) {
  const float* x    = (const float*)d_in[0];
  const float* ln_g = (const float*)d_in[1];
  const float* ln_b = (const float*)d_in[2];
  const float* uv_w = (const float*)d_in[3];
  const float* uv_b = (const float*)d_in[4];
  const float* qk_w = (const float*)d_in[5];
  const float* qk_b = (const float*)d_in[6];
  const float* o_w  = (const float*)d_in[7];
  const float* o_b  = (const float*)d_in[8];
  float* out = (float*)d_out;

  const int H = 1024, E = 2048, S = 128;
  const int NU = 2 * E + S;          // 4224
  const int n = in_sizes[0] / H;     // 4096

  char* p = (char*)d_ws;
  unsigned short* h_bf   = (unsigned short*)p; p += (size_t)n * H * 2;
  unsigned short* uvw_bf = (unsigned short*)p; p += (size_t)NU * H * 2;
  unsigned short* ow_bf  = (unsigned short*)p; p += (size_t)H * E * 2;
  unsigned short* uv_bf  = (unsigned short*)p; p += (size_t)n * NU * 2;
  unsigned short* q_bf   = (unsigned short*)p; p += (size_t)n * S * 2;
  unsigned short* k_bf   = (unsigned short*)p; p += (size_t)n * S * 2;
  unsigned short* vT_bf  = (unsigned short*)p; p += (size_t)E * n * 2;
  unsigned short* ker_bf = (unsigned short*)p; p += (size_t)n * n * 2;
  unsigned short* ug_bf  = (unsigned short*)p; p += (size_t)n * E * 2;

  int n4;
  n4 = NU * H / 4; cvt_kernel<<<(n4 + 255) / 256, 256, 0, stream>>>(uv_w, uvw_bf, n4);
  n4 = H * E / 4;  cvt_kernel<<<(n4 + 255) / 256, 256, 0, stream>>>(o_w, ow_bf, n4);

  ln_kernel<<<n, 256, 0, stream>>>(x, ln_g, ln_b, h_bf);

  // uv = silu(h @ uv_w^T + uv_b)   M=4096 N=4224 K=1024
  gemm_pipe<0><<<dim3(n / 256, NU / 128), 512, 0, stream>>>(
      h_bf, H, uvw_bf, H, uv_bf, NU, H, uv_b, nullptr, 0, nullptr, 0);

  int tq = n * S;
  qk_kernel<<<(tq + 255) / 256, 256, 0, stream>>>(uv_bf, qk_w, qk_b, q_bf, k_bf, NU, 2 * E, S, tq);

  transpose_v<<<dim3(n / 64, E / 64), 256, 0, stream>>>(uv_bf, vT_bf, n, NU, E);

  // kernel = relu(q @ k^T / sqrt(128))^2   M=N=4096 K=128 (old path)
  gemm_bt<1><<<dim3(n / 128, n / 128), 256, 0, stream>>>(
      q_bf, S, k_bf, S, ker_bf, n, S);

  // ug = u * (kernel @ v)   M=4096 N=2048 K=4096
  gemm_pipe<2><<<dim3(n / 256, E / 128), 512, 0, stream>>>(
      ker_bf, n, vT_bf, n, ug_bf, E, n, nullptr, uv_bf, NU, nullptr, 0);

  // out = ug @ o_w^T + o_b + x   M=4096 N=1024 K=2048
  gemm_pipe<3><<<dim3(n / 256, H / 128), 512, 0, stream>>>(
      ug_bf, E, ow_bf, E, out, H, E, o_b, nullptr, 0, x, H);
}